// Round 1
// baseline (907.292 us; speedup 1.0000x reference)
//
#include <hip/hip_runtime.h>

#define H 128

// ---------------------------------------------------------------------------
// Workspace layout (floats):
//   consts[1024] : [0]=a1, [1]=c1, [2..129]=u2, [130..257]=c2, [258..385]=u3,
//                  [386..513]=c3
//   bufA[N*128]  : agg2 (zeroed) -> h2 (in-place after mlp2)
//   bufB[N*128]  : agg3 (zeroed)
//   s1[N], p[N], q[N]
// Total ~51.3 MB.
// edge_index treated as int32 (JAX default x64-disabled downcasts int64).
// ---------------------------------------------------------------------------

__device__ __forceinline__ float4 f4fma(float s, float4 w, float4 a) {
  a.x = fmaf(s, w.x, a.x); a.y = fmaf(s, w.y, a.y);
  a.z = fmaf(s, w.z, a.z); a.w = fmaf(s, w.w, a.w);
  return a;
}

// u2[k] = em_w . l2_w[:,k];  c2[k] = em_b . l2_w[:,k] + l2_b[k] + n1_b[k]
// u3[k] = em_w . l3_w[:,k];  c3[k] = em_b . l3_w[:,k] + l3_b[k]
// a1 = em_w . l1_w;          c1 = em_b . l1_w + l1_b
__global__ void precompute_kernel(
    const float* __restrict__ em_w, const float* __restrict__ em_b,
    const float* __restrict__ l1_w, const float* __restrict__ l1_b,
    const float* __restrict__ l2_w, const float* __restrict__ l2_b,
    const float* __restrict__ n1_b,
    const float* __restrict__ l3_w, const float* __restrict__ l3_b,
    float* __restrict__ consts) {
  const int k = threadIdx.x;  // 0..127
  float u2 = 0.f, c2 = 0.f, u3 = 0.f, c3 = 0.f;
  for (int j = 0; j < H; ++j) {
    const float ew = em_w[j], eb = em_b[j];
    u2 = fmaf(ew, l2_w[j * H + k], u2);
    c2 = fmaf(eb, l2_w[j * H + k], c2);
    u3 = fmaf(ew, l3_w[j * H + k], u3);
    c3 = fmaf(eb, l3_w[j * H + k], c3);
  }
  consts[2 + k]         = u2;
  consts[2 + H + k]     = c2 + l2_b[k] + n1_b[k];
  consts[2 + 2 * H + k] = u3;
  consts[2 + 3 * H + k] = c3 + l3_b[k];
  __shared__ float sa[H], sc[H];
  sa[k] = em_w[k] * l1_w[k];
  sc[k] = em_b[k] * l1_w[k];
  __syncthreads();
  for (int s = 64; s > 0; s >>= 1) {
    if (k < s) { sa[k] += sa[k + s]; sc[k] += sc[k + s]; }
    __syncthreads();
  }
  if (k == 0) { consts[0] = sa[0]; consts[1] = sc[0] + l1_b[0]; }
}

__global__ void init_s1_kernel(const float* __restrict__ x,
                               float* __restrict__ s1, int N) {
  const int n = blockIdx.x * blockDim.x + threadIdx.x;
  if (n < N) s1[n] = x[n];
}

// layer-1 messages are scalars: s1[dst] += relu(x[src] + a1*ea + c1)
__global__ void edge1_kernel(const int* __restrict__ src,
                             const int* __restrict__ dst,
                             const float* __restrict__ ea,
                             const float* __restrict__ x,
                             const float* __restrict__ consts,
                             float* __restrict__ s1, int E) {
  const int e = blockIdx.x * blockDim.x + threadIdx.x;
  if (e >= E) return;
  const float m = fmaxf(fmaf(consts[0], ea[e], consts[1]) + x[src[e]], 0.f);
  unsafeAtomicAdd(&s1[dst[e]], m);
}

// layer-2 messages: agg[dst,k] += relu(s1[src]*n1w[k] + ea*u2[k] + c2[k])
// thread -> (edge, k); k constant across grid-stride (stride % 128 == 0)
__global__ void edge2_kernel(const int* __restrict__ src,
                             const int* __restrict__ dst,
                             const float* __restrict__ ea,
                             const float* __restrict__ s1,
                             const float* __restrict__ n1w,
                             const float* __restrict__ consts,
                             float* __restrict__ agg, int E) {
  const int k = threadIdx.x & (H - 1);
  const float w = n1w[k];
  const float u = consts[2 + k];
  const float c = consts[2 + H + k];
  const int total = E * H;
  const int stride = gridDim.x * blockDim.x;
  for (int idx = blockIdx.x * blockDim.x + threadIdx.x; idx < total; idx += stride) {
    const int e = idx >> 7;
    const float m = fmaxf(fmaf(s1[src[e]], w, fmaf(ea[e], u, c)), 0.f);
    unsafeAtomicAdd(&agg[dst[e] * H + k], m);
  }
}

// layer-3 messages: agg[dst,k] += relu(h2[src,k] + ea*u3[k] + c3[k])
__global__ void edge3_kernel(const int* __restrict__ src,
                             const int* __restrict__ dst,
                             const float* __restrict__ ea,
                             const float* __restrict__ h2,
                             const float* __restrict__ consts,
                             float* __restrict__ agg, int E) {
  const int k = threadIdx.x & (H - 1);
  const float u = consts[2 + 2 * H + k];
  const float c = consts[2 + 3 * H + k];
  const int total = E * H;
  const int stride = gridDim.x * blockDim.x;
  for (int idx = blockIdx.x * blockDim.x + threadIdx.x; idx < total; idx += stride) {
    const int e = idx >> 7;
    const float m = fmaxf(h2[src[e] * H + k] + fmaf(ea[e], u, c), 0.f);
    unsafeAtomicAdd(&agg[dst[e] * H + k], m);
  }
}

// h2 = (s1[n]*n1w + n1b + agg2[n,:]) @ n2w + n2b   (in-place over buf)
// block=256: 32-node tile; thread = (kv 0..31 -> 4 k's, ng 0..7 -> 4 nodes)
__global__ __launch_bounds__(256) void mlp2_kernel(
    float* __restrict__ buf, const float* __restrict__ s1,
    const float* __restrict__ n1w, const float* __restrict__ n1b,
    const float* __restrict__ n2w, const float* __restrict__ n2b, int N) {
  __shared__ float W[H * H];     // 64 KB
  __shared__ float t[32][H];     // 16 KB
  const int tid = threadIdx.x;
  for (int i = tid; i < H * H; i += 256) W[i] = n2w[i];
  const int kv = tid & 31;
  const int ng = tid >> 5;
  const float4* W4 = (const float4*)W;
  const float4 bias = ((const float4*)n2b)[kv];
  for (int tile = blockIdx.x * 32; tile < N; tile += gridDim.x * 32) {
    __syncthreads();
    const int nmax = min(32, N - tile);
    for (int i = tid; i < nmax * H; i += 256) {
      const int nn = i >> 7, j = i & (H - 1);
      const int n = tile + nn;
      t[nn][j] = fmaf(s1[n], n1w[j], n1b[j]) + buf[n * H + j];
    }
    __syncthreads();
    float4 acc[4];
    acc[0] = acc[1] = acc[2] = acc[3] = make_float4(0.f, 0.f, 0.f, 0.f);
    for (int j = 0; j < H; j += 4) {
      const float4 w0 = W4[(j + 0) * 32 + kv];
      const float4 w1 = W4[(j + 1) * 32 + kv];
      const float4 w2 = W4[(j + 2) * 32 + kv];
      const float4 w3 = W4[(j + 3) * 32 + kv];
#pragma unroll
      for (int m = 0; m < 4; ++m) {
        const float4 tm = *(const float4*)&t[4 * ng + m][j];
        acc[m] = f4fma(tm.x, w0, acc[m]);
        acc[m] = f4fma(tm.y, w1, acc[m]);
        acc[m] = f4fma(tm.z, w2, acc[m]);
        acc[m] = f4fma(tm.w, w3, acc[m]);
      }
    }
#pragma unroll
    for (int m = 0; m < 4; ++m) {
      const int nn = 4 * ng + m;
      const int n = tile + nn;
      if (nn < nmax) {
        float4 o;
        o.x = acc[m].x + bias.x; o.y = acc[m].y + bias.y;
        o.z = acc[m].z + bias.z; o.w = acc[m].w + bias.w;
        ((float4*)buf)[n * 32 + kv] = o;
      }
    }
  }
}

// h3 = (h2 + agg3) @ n3w + n3b; p[n] = h3 . dec_w[:128]; q[n] = h3 . dec_w[128:]
__global__ __launch_bounds__(256) void mlp3_kernel(
    const float* __restrict__ bufA, const float* __restrict__ bufB,
    const float* __restrict__ n3w, const float* __restrict__ n3b,
    const float* __restrict__ dec_w,
    float* __restrict__ p, float* __restrict__ q, int N) {
  __shared__ float W[H * H];
  __shared__ float t[32][H];
  const int tid = threadIdx.x;
  for (int i = tid; i < H * H; i += 256) W[i] = n3w[i];
  const int kv = tid & 31;
  const int ng = tid >> 5;
  const float4* W4 = (const float4*)W;
  const float4 bias = ((const float4*)n3b)[kv];
  const float4 dwA = ((const float4*)dec_w)[kv];
  const float4 dwB = ((const float4*)(dec_w + H))[kv];
  for (int tile = blockIdx.x * 32; tile < N; tile += gridDim.x * 32) {
    __syncthreads();
    const int nmax = min(32, N - tile);
    for (int i = tid; i < nmax * H; i += 256) {
      const int nn = i >> 7, j = i & (H - 1);
      const int n = tile + nn;
      t[nn][j] = bufA[n * H + j] + bufB[n * H + j];
    }
    __syncthreads();
    float4 acc[4];
    acc[0] = acc[1] = acc[2] = acc[3] = make_float4(0.f, 0.f, 0.f, 0.f);
    for (int j = 0; j < H; j += 4) {
      const float4 w0 = W4[(j + 0) * 32 + kv];
      const float4 w1 = W4[(j + 1) * 32 + kv];
      const float4 w2 = W4[(j + 2) * 32 + kv];
      const float4 w3 = W4[(j + 3) * 32 + kv];
#pragma unroll
      for (int m = 0; m < 4; ++m) {
        const float4 tm = *(const float4*)&t[4 * ng + m][j];
        acc[m] = f4fma(tm.x, w0, acc[m]);
        acc[m] = f4fma(tm.y, w1, acc[m]);
        acc[m] = f4fma(tm.z, w2, acc[m]);
        acc[m] = f4fma(tm.w, w3, acc[m]);
      }
    }
#pragma unroll
    for (int m = 0; m < 4; ++m) {
      float4 h;
      h.x = acc[m].x + bias.x; h.y = acc[m].y + bias.y;
      h.z = acc[m].z + bias.z; h.w = acc[m].w + bias.w;
      float pd = h.x * dwA.x + h.y * dwA.y + h.z * dwA.z + h.w * dwA.w;
      float qd = h.x * dwB.x + h.y * dwB.y + h.z * dwB.z + h.w * dwB.w;
#pragma unroll
      for (int o = 16; o >= 1; o >>= 1) {
        pd += __shfl_xor(pd, o, 64);
        qd += __shfl_xor(qd, o, 64);
      }
      const int n = tile + 4 * ng + m;
      if (kv == 0 && 4 * ng + m < nmax) { p[n] = pd; q[n] = qd; }
    }
  }
}

__global__ void final_kernel(const int* __restrict__ src,
                             const int* __restrict__ dst,
                             const float* __restrict__ p,
                             const float* __restrict__ q,
                             const float* __restrict__ dec_b,
                             float* __restrict__ out, int E) {
  const int e = blockIdx.x * blockDim.x + threadIdx.x;
  if (e < E) out[e] = p[src[e]] + q[dst[e]] + dec_b[0];
}

extern "C" void kernel_launch(void* const* d_in, const int* in_sizes, int n_in,
                              void* d_out, int out_size, void* d_ws, size_t ws_size,
                              hipStream_t stream) {
  const float* x     = (const float*)d_in[0];
  const int*   ei    = (const int*)d_in[1];
  const float* ea    = (const float*)d_in[2];
  const float* em_w  = (const float*)d_in[3];
  const float* em_b  = (const float*)d_in[4];
  const float* l1_w  = (const float*)d_in[5];
  const float* l1_b  = (const float*)d_in[6];
  const float* n1_w  = (const float*)d_in[7];
  const float* n1_b  = (const float*)d_in[8];
  const float* l2_w  = (const float*)d_in[9];
  const float* l2_b  = (const float*)d_in[10];
  const float* n2_w  = (const float*)d_in[11];
  const float* n2_b  = (const float*)d_in[12];
  const float* l3_w  = (const float*)d_in[13];
  const float* l3_b  = (const float*)d_in[14];
  const float* n3_w  = (const float*)d_in[15];
  const float* n3_b  = (const float*)d_in[16];
  const float* dec_w = (const float*)d_in[17];
  const float* dec_b = (const float*)d_in[18];
  float* out = (float*)d_out;

  const int N = in_sizes[0];
  const int E = in_sizes[2];
  const int* src = ei;
  const int* dst = ei + E;

  float* ws     = (float*)d_ws;
  float* consts = ws;
  float* bufA   = ws + 1024;
  float* bufB   = bufA + (size_t)N * H;
  float* s1     = bufB + (size_t)N * H;
  float* p      = s1 + N;
  float* q      = p + N;

  hipMemsetAsync(bufA, 0, (size_t)N * H * sizeof(float), stream);
  hipMemsetAsync(bufB, 0, (size_t)N * H * sizeof(float), stream);

  precompute_kernel<<<1, 128, 0, stream>>>(em_w, em_b, l1_w, l1_b, l2_w, l2_b,
                                           n1_b, l3_w, l3_b, consts);
  init_s1_kernel<<<(N + 255) / 256, 256, 0, stream>>>(x, s1, N);
  edge1_kernel<<<(E + 255) / 256, 256, 0, stream>>>(src, dst, ea, x, consts, s1, E);
  edge2_kernel<<<8192, 256, 0, stream>>>(src, dst, ea, s1, n1_w, consts, bufA, E);
  mlp2_kernel<<<512, 256, 0, stream>>>(bufA, s1, n1_w, n1_b, n2_w, n2_b, N);
  edge3_kernel<<<8192, 256, 0, stream>>>(src, dst, ea, bufA, consts, bufB, E);
  mlp3_kernel<<<512, 256, 0, stream>>>(bufA, bufB, n3_w, n3_b, dec_w, p, q, N);
  final_kernel<<<(E + 255) / 256, 256, 0, stream>>>(src, dst, p, q, dec_b, out, E);
}

// Round 2
// 456.348 us; speedup vs baseline: 1.9882x; 1.9882x over previous
//
#include <hip/hip_runtime.h>

#define H 128

// ---------------------------------------------------------------------------
// Strategy (R1): CSR-by-dst counting sort, then atomic-free wave-per-node
// aggregation (register accumulators, one coalesced row store per node).
//
// Workspace layout (4-byte units):
//   consts[1024] : [0]=a1,[1]=c1,[2..]=u2,c2,u3,c3
//   bufA[N*128]  : t2 (edge2 out) -> h2 (mlp2 in-place)
//   bufB[N*128]  : t3 (edge3 out); its first N ints double as scatter cursor
//   s1[N], p[N], q[N]
//   deg[N], rowstart[N+1], srcp[E], eap[E]
// ---------------------------------------------------------------------------

__device__ __forceinline__ float4 f4fma(float s, float4 w, float4 a) {
  a.x = fmaf(s, w.x, a.x); a.y = fmaf(s, w.y, a.y);
  a.z = fmaf(s, w.z, a.z); a.w = fmaf(s, w.w, a.w);
  return a;
}

__global__ void precompute_kernel(
    const float* __restrict__ em_w, const float* __restrict__ em_b,
    const float* __restrict__ l1_w, const float* __restrict__ l1_b,
    const float* __restrict__ l2_w, const float* __restrict__ l2_b,
    const float* __restrict__ n1_b,
    const float* __restrict__ l3_w, const float* __restrict__ l3_b,
    float* __restrict__ consts) {
  const int k = threadIdx.x;  // 0..127
  float u2 = 0.f, c2 = 0.f, u3 = 0.f, c3 = 0.f;
  for (int j = 0; j < H; ++j) {
    const float ew = em_w[j], eb = em_b[j];
    u2 = fmaf(ew, l2_w[j * H + k], u2);
    c2 = fmaf(eb, l2_w[j * H + k], c2);
    u3 = fmaf(ew, l3_w[j * H + k], u3);
    c3 = fmaf(eb, l3_w[j * H + k], c3);
  }
  consts[2 + k]         = u2;
  consts[2 + H + k]     = c2 + l2_b[k] + n1_b[k];
  consts[2 + 2 * H + k] = u3;
  consts[2 + 3 * H + k] = c3 + l3_b[k];
  __shared__ float sa[H], sc[H];
  sa[k] = em_w[k] * l1_w[k];
  sc[k] = em_b[k] * l1_w[k];
  __syncthreads();
  for (int s = 64; s > 0; s >>= 1) {
    if (k < s) { sa[k] += sa[k + s]; sc[k] += sc[k + s]; }
    __syncthreads();
  }
  if (k == 0) { consts[0] = sa[0]; consts[1] = sc[0] + l1_b[0]; }
}

// ------------------------- CSR build -------------------------

__global__ void hist_kernel(const int* __restrict__ dst, int* __restrict__ deg,
                            int E) {
  const int e = blockIdx.x * blockDim.x + threadIdx.x;
  if (e < E) atomicAdd(&deg[dst[e]], 1);
}

// single-block chunked Hillis-Steele exclusive scan; also copies to cursor
__global__ __launch_bounds__(1024) void scan_kernel(
    const int* __restrict__ deg, int* __restrict__ rowstart,
    int* __restrict__ cursor, int N) {
  __shared__ int sd[1024];
  __shared__ int carry_s;
  const int tid = threadIdx.x;
  if (tid == 0) carry_s = 0;
  __syncthreads();
  for (int base = 0; base < N; base += 1024) {
    const int idx = base + tid;
    const int v = (idx < N) ? deg[idx] : 0;
    sd[tid] = v;
    __syncthreads();
    for (int off = 1; off < 1024; off <<= 1) {
      const int t = (tid >= off) ? sd[tid - off] : 0;
      __syncthreads();
      sd[tid] += t;
      __syncthreads();
    }
    const int carry = carry_s;
    if (idx < N) {
      const int excl = carry + sd[tid] - v;
      rowstart[idx] = excl;
      cursor[idx] = excl;
    }
    __syncthreads();
    if (tid == 1023) carry_s = carry + sd[1023];
    __syncthreads();
  }
  if (tid == 0) rowstart[N] = carry_s;
}

__global__ void scatter_kernel(const int* __restrict__ src,
                               const int* __restrict__ dst,
                               const float* __restrict__ ea,
                               int* __restrict__ cursor,
                               int* __restrict__ srcp,
                               float* __restrict__ eap, int E) {
  const int e = blockIdx.x * blockDim.x + threadIdx.x;
  if (e >= E) return;
  const int pos = atomicAdd(&cursor[dst[e]], 1);
  srcp[pos] = src[e];
  eap[pos] = ea[e];
}

// ------------------------- layer 1 (scalar) -------------------------
// s1[n] = x[n] + sum_{e in-edges} relu(x[src] + a1*ea + c1); wave per node
__global__ __launch_bounds__(256) void edge1_csr(
    const int* __restrict__ rowstart, const int* __restrict__ srcp,
    const float* __restrict__ eap, const float* __restrict__ x,
    const float* __restrict__ consts, float* __restrict__ s1, int N) {
  const int n = (blockIdx.x * blockDim.x + threadIdx.x) >> 6;
  const int lane = threadIdx.x & 63;
  if (n >= N) return;
  const int rs = rowstart[n], re = rowstart[n + 1];
  const float a1 = consts[0], c1 = consts[1];
  float part = 0.f;
  for (int i = rs + lane; i < re; i += 64)
    part += fmaxf(x[srcp[i]] + fmaf(a1, eap[i], c1), 0.f);
#pragma unroll
  for (int o = 32; o >= 1; o >>= 1) part += __shfl_xor(part, o, 64);
  if (lane == 0) s1[n] = x[n] + part;
}

// ------------------------- layer 2 -------------------------
// t2[n,k] = s1[n]*n1w[k] + n1b[k] + sum relu(s1[src]*n1w[k] + ea*u2[k] + c2[k])
// wave per node; lane handles k=lane and k=lane+64; edges broadcast via shfl
__global__ __launch_bounds__(256) void edge2_csr(
    const int* __restrict__ rowstart, const int* __restrict__ srcp,
    const float* __restrict__ eap, const float* __restrict__ s1,
    const float* __restrict__ n1w, const float* __restrict__ n1b,
    const float* __restrict__ consts, float* __restrict__ t2, int N) {
  const int n = (blockIdx.x * blockDim.x + threadIdx.x) >> 6;
  const int lane = threadIdx.x & 63;
  if (n >= N) return;
  const int rs = rowstart[n], re = rowstart[n + 1];
  const float w0 = n1w[lane],          w1 = n1w[lane + 64];
  const float u0 = consts[2 + lane],   u1 = consts[2 + lane + 64];
  const float c0 = consts[2 + H + lane], c1 = consts[2 + H + lane + 64];
  float acc0 = 0.f, acc1 = 0.f;
  for (int base = rs; base < re; base += 64) {
    const int i = base + lane;
    float s1v = 0.f, eav = 0.f;
    if (i < re) { s1v = s1[srcp[i]]; eav = eap[i]; }
    const int cnt = min(64, re - base);
    for (int j = 0; j < cnt; ++j) {
      const float s = __shfl(s1v, j, 64);
      const float a = __shfl(eav, j, 64);
      acc0 += fmaxf(fmaf(s, w0, fmaf(a, u0, c0)), 0.f);
      acc1 += fmaxf(fmaf(s, w1, fmaf(a, u1, c1)), 0.f);
    }
  }
  const float sn = s1[n];
  t2[(size_t)n * H + lane]      = fmaf(sn, w0, n1b[lane])      + acc0;
  t2[(size_t)n * H + lane + 64] = fmaf(sn, w1, n1b[lane + 64]) + acc1;
}

// ------------------------- layer 3 -------------------------
// t3[n,k] = h2[n,k] + sum relu(h2[src,k] + ea*u3[k] + c3[k]); wave per node
__global__ __launch_bounds__(256) void edge3_csr(
    const int* __restrict__ rowstart, const int* __restrict__ srcp,
    const float* __restrict__ eap, const float* __restrict__ h2,
    const float* __restrict__ consts, float* __restrict__ t3, int N) {
  const int n = (blockIdx.x * blockDim.x + threadIdx.x) >> 6;
  const int lane = threadIdx.x & 63;
  if (n >= N) return;
  const int rs = rowstart[n], re = rowstart[n + 1];
  const float u0 = consts[2 + 2 * H + lane], u1 = consts[2 + 2 * H + lane + 64];
  const float c0 = consts[2 + 3 * H + lane], c1 = consts[2 + 3 * H + lane + 64];
  float acc0 = 0.f, acc1 = 0.f;
  int i = rs;
  for (; i + 4 <= re; i += 4) {
    const int s0 = srcp[i], s1i = srcp[i + 1], s2 = srcp[i + 2], s3 = srcp[i + 3];
    const float a0 = eap[i], a1 = eap[i + 1], a2 = eap[i + 2], a3 = eap[i + 3];
    const float h00 = h2[(size_t)s0 * H + lane];
    const float h01 = h2[(size_t)s0 * H + lane + 64];
    const float h10 = h2[(size_t)s1i * H + lane];
    const float h11 = h2[(size_t)s1i * H + lane + 64];
    const float h20 = h2[(size_t)s2 * H + lane];
    const float h21 = h2[(size_t)s2 * H + lane + 64];
    const float h30 = h2[(size_t)s3 * H + lane];
    const float h31 = h2[(size_t)s3 * H + lane + 64];
    acc0 += fmaxf(h00 + fmaf(a0, u0, c0), 0.f);
    acc1 += fmaxf(h01 + fmaf(a0, u1, c1), 0.f);
    acc0 += fmaxf(h10 + fmaf(a1, u0, c0), 0.f);
    acc1 += fmaxf(h11 + fmaf(a1, u1, c1), 0.f);
    acc0 += fmaxf(h20 + fmaf(a2, u0, c0), 0.f);
    acc1 += fmaxf(h21 + fmaf(a2, u1, c1), 0.f);
    acc0 += fmaxf(h30 + fmaf(a3, u0, c0), 0.f);
    acc1 += fmaxf(h31 + fmaf(a3, u1, c1), 0.f);
  }
  for (; i < re; ++i) {
    const int s = srcp[i];
    const float a = eap[i];
    acc0 += fmaxf(h2[(size_t)s * H + lane]      + fmaf(a, u0, c0), 0.f);
    acc1 += fmaxf(h2[(size_t)s * H + lane + 64] + fmaf(a, u1, c1), 0.f);
  }
  t3[(size_t)n * H + lane]      = h2[(size_t)n * H + lane]      + acc0;
  t3[(size_t)n * H + lane + 64] = h2[(size_t)n * H + lane + 64] + acc1;
}

// ------------------------- node MLPs -------------------------
// h2 = t2 @ n2w + n2b (in-place over buf)
__global__ __launch_bounds__(256) void mlp2_kernel(
    float* __restrict__ buf, const float* __restrict__ n2w,
    const float* __restrict__ n2b, int N) {
  __shared__ float W[H * H];
  __shared__ float t[32][H];
  const int tid = threadIdx.x;
  for (int i = tid; i < H * H; i += 256) W[i] = n2w[i];
  const int kv = tid & 31;
  const int ng = tid >> 5;
  const float4* W4 = (const float4*)W;
  const float4 bias = ((const float4*)n2b)[kv];
  for (int tile = blockIdx.x * 32; tile < N; tile += gridDim.x * 32) {
    __syncthreads();
    const int nmax = min(32, N - tile);
    for (int i = tid; i < nmax * 32; i += 256) {
      const int nn = i >> 5, j4 = i & 31;
      ((float4*)&t[nn][0])[j4] = ((const float4*)(buf + (size_t)(tile + nn) * H))[j4];
    }
    __syncthreads();
    float4 acc[4];
    acc[0] = acc[1] = acc[2] = acc[3] = make_float4(0.f, 0.f, 0.f, 0.f);
    for (int j = 0; j < H; j += 4) {
      const float4 w0 = W4[(j + 0) * 32 + kv];
      const float4 w1 = W4[(j + 1) * 32 + kv];
      const float4 w2 = W4[(j + 2) * 32 + kv];
      const float4 w3 = W4[(j + 3) * 32 + kv];
#pragma unroll
      for (int m = 0; m < 4; ++m) {
        const float4 tm = *(const float4*)&t[4 * ng + m][j];
        acc[m] = f4fma(tm.x, w0, acc[m]);
        acc[m] = f4fma(tm.y, w1, acc[m]);
        acc[m] = f4fma(tm.z, w2, acc[m]);
        acc[m] = f4fma(tm.w, w3, acc[m]);
      }
    }
#pragma unroll
    for (int m = 0; m < 4; ++m) {
      const int nn = 4 * ng + m;
      if (nn < nmax) {
        float4 o;
        o.x = acc[m].x + bias.x; o.y = acc[m].y + bias.y;
        o.z = acc[m].z + bias.z; o.w = acc[m].w + bias.w;
        ((float4*)buf)[(size_t)(tile + nn) * 32 + kv] = o;
      }
    }
  }
}

// h3 = t3 @ n3w + n3b; p[n]=h3.dec_w[:128]; q[n]=h3.dec_w[128:]
__global__ __launch_bounds__(256) void mlp3_kernel(
    const float* __restrict__ t3, const float* __restrict__ n3w,
    const float* __restrict__ n3b, const float* __restrict__ dec_w,
    float* __restrict__ p, float* __restrict__ q, int N) {
  __shared__ float W[H * H];
  __shared__ float t[32][H];
  const int tid = threadIdx.x;
  for (int i = tid; i < H * H; i += 256) W[i] = n3w[i];
  const int kv = tid & 31;
  const int ng = tid >> 5;
  const float4* W4 = (const float4*)W;
  const float4 bias = ((const float4*)n3b)[kv];
  const float4 dwA = ((const float4*)dec_w)[kv];
  const float4 dwB = ((const float4*)(dec_w + H))[kv];
  for (int tile = blockIdx.x * 32; tile < N; tile += gridDim.x * 32) {
    __syncthreads();
    const int nmax = min(32, N - tile);
    for (int i = tid; i < nmax * 32; i += 256) {
      const int nn = i >> 5, j4 = i & 31;
      ((float4*)&t[nn][0])[j4] = ((const float4*)(t3 + (size_t)(tile + nn) * H))[j4];
    }
    __syncthreads();
    float4 acc[4];
    acc[0] = acc[1] = acc[2] = acc[3] = make_float4(0.f, 0.f, 0.f, 0.f);
    for (int j = 0; j < H; j += 4) {
      const float4 w0 = W4[(j + 0) * 32 + kv];
      const float4 w1 = W4[(j + 1) * 32 + kv];
      const float4 w2 = W4[(j + 2) * 32 + kv];
      const float4 w3 = W4[(j + 3) * 32 + kv];
#pragma unroll
      for (int m = 0; m < 4; ++m) {
        const float4 tm = *(const float4*)&t[4 * ng + m][j];
        acc[m] = f4fma(tm.x, w0, acc[m]);
        acc[m] = f4fma(tm.y, w1, acc[m]);
        acc[m] = f4fma(tm.z, w2, acc[m]);
        acc[m] = f4fma(tm.w, w3, acc[m]);
      }
    }
#pragma unroll
    for (int m = 0; m < 4; ++m) {
      float4 h;
      h.x = acc[m].x + bias.x; h.y = acc[m].y + bias.y;
      h.z = acc[m].z + bias.z; h.w = acc[m].w + bias.w;
      float pd = h.x * dwA.x + h.y * dwA.y + h.z * dwA.z + h.w * dwA.w;
      float qd = h.x * dwB.x + h.y * dwB.y + h.z * dwB.z + h.w * dwB.w;
#pragma unroll
      for (int o = 16; o >= 1; o >>= 1) {
        pd += __shfl_xor(pd, o, 64);
        qd += __shfl_xor(qd, o, 64);
      }
      const int n = tile + 4 * ng + m;
      if (kv == 0 && 4 * ng + m < nmax) { p[n] = pd; q[n] = qd; }
    }
  }
}

__global__ void final_kernel(const int* __restrict__ src,
                             const int* __restrict__ dst,
                             const float* __restrict__ p,
                             const float* __restrict__ q,
                             const float* __restrict__ dec_b,
                             float* __restrict__ out, int E) {
  const int e = blockIdx.x * blockDim.x + threadIdx.x;
  if (e < E) out[e] = p[src[e]] + q[dst[e]] + dec_b[0];
}

extern "C" void kernel_launch(void* const* d_in, const int* in_sizes, int n_in,
                              void* d_out, int out_size, void* d_ws, size_t ws_size,
                              hipStream_t stream) {
  const float* x     = (const float*)d_in[0];
  const int*   ei    = (const int*)d_in[1];
  const float* ea    = (const float*)d_in[2];
  const float* em_w  = (const float*)d_in[3];
  const float* em_b  = (const float*)d_in[4];
  const float* l1_w  = (const float*)d_in[5];
  const float* l1_b  = (const float*)d_in[6];
  const float* n1_w  = (const float*)d_in[7];
  const float* n1_b  = (const float*)d_in[8];
  const float* l2_w  = (const float*)d_in[9];
  const float* l2_b  = (const float*)d_in[10];
  const float* n2_w  = (const float*)d_in[11];
  const float* n2_b  = (const float*)d_in[12];
  const float* l3_w  = (const float*)d_in[13];
  const float* l3_b  = (const float*)d_in[14];
  const float* n3_w  = (const float*)d_in[15];
  const float* n3_b  = (const float*)d_in[16];
  const float* dec_w = (const float*)d_in[17];
  const float* dec_b = (const float*)d_in[18];
  float* out = (float*)d_out;

  const int N = in_sizes[0];
  const int E = in_sizes[2];
  const int* src = ei;
  const int* dst = ei + E;

  float* ws       = (float*)d_ws;
  float* consts   = ws;
  float* bufA     = ws + 1024;                      // t2 -> h2
  float* bufB     = bufA + (size_t)N * H;           // t3 (first N ints = cursor)
  float* s1       = bufB + (size_t)N * H;
  float* p        = s1 + N;
  float* q        = p + N;
  int*   deg      = (int*)(q + N);
  int*   rowstart = deg + N;                        // N+1
  int*   srcp     = rowstart + N + 1;               // E
  float* eap      = (float*)(srcp + E);             // E
  int*   cursor   = (int*)bufB;                     // aliased: dead before edge3

  hipMemsetAsync(deg, 0, (size_t)N * sizeof(int), stream);

  precompute_kernel<<<1, 128, 0, stream>>>(em_w, em_b, l1_w, l1_b, l2_w, l2_b,
                                           n1_b, l3_w, l3_b, consts);
  hist_kernel<<<(E + 255) / 256, 256, 0, stream>>>(dst, deg, E);
  scan_kernel<<<1, 1024, 0, stream>>>(deg, rowstart, cursor, N);
  scatter_kernel<<<(E + 255) / 256, 256, 0, stream>>>(src, dst, ea, cursor,
                                                      srcp, eap, E);

  const int nwblocks = (N + 3) / 4;  // 4 waves (nodes) per 256-thread block
  edge1_csr<<<nwblocks, 256, 0, stream>>>(rowstart, srcp, eap, x, consts, s1, N);
  edge2_csr<<<nwblocks, 256, 0, stream>>>(rowstart, srcp, eap, s1, n1_w, n1_b,
                                          consts, bufA, N);
  mlp2_kernel<<<512, 256, 0, stream>>>(bufA, n2_w, n2_b, N);
  edge3_csr<<<nwblocks, 256, 0, stream>>>(rowstart, srcp, eap, bufA, consts,
                                          bufB, N);
  mlp3_kernel<<<512, 256, 0, stream>>>(bufB, n3_w, n3_b, dec_w, p, q, N);
  final_kernel<<<(E + 255) / 256, 256, 0, stream>>>(src, dst, p, q, dec_b, out, E);
}

// Round 3
// 369.442 us; speedup vs baseline: 2.4558x; 1.2352x over previous
//
#include <hip/hip_runtime.h>

#define H 128

// ---------------------------------------------------------------------------
// R2: multi-block scan (R1's single-block scan_kernel was 94 us @ 0.17% occ).
// Three-phase: scan_partial (49 blks local scan + block sums) ->
// scan_bsums (1 wave scans 49 sums) -> scan_fixup (apply offsets).
//
// Workspace layout (4-byte units):
//   consts[1024] : [0]=a1,[1]=c1,[2..]=u2,c2,u3,c3
//   bufA[N*128]  : t2 (edge2 out) -> h2 (mlp2 in-place)
//   bufB[N*128]  : t3 (edge3 out); its first N ints double as scatter cursor
//   s1[N], p[N], q[N]
//   deg[N], rowstart[N+1], srcp[E], eap[E], bsum[64], bo[65]
// ---------------------------------------------------------------------------

__device__ __forceinline__ float4 f4fma(float s, float4 w, float4 a) {
  a.x = fmaf(s, w.x, a.x); a.y = fmaf(s, w.y, a.y);
  a.z = fmaf(s, w.z, a.z); a.w = fmaf(s, w.w, a.w);
  return a;
}

__global__ void precompute_kernel(
    const float* __restrict__ em_w, const float* __restrict__ em_b,
    const float* __restrict__ l1_w, const float* __restrict__ l1_b,
    const float* __restrict__ l2_w, const float* __restrict__ l2_b,
    const float* __restrict__ n1_b,
    const float* __restrict__ l3_w, const float* __restrict__ l3_b,
    float* __restrict__ consts) {
  const int k = threadIdx.x;  // 0..127
  float u2 = 0.f, c2 = 0.f, u3 = 0.f, c3 = 0.f;
  for (int j = 0; j < H; ++j) {
    const float ew = em_w[j], eb = em_b[j];
    u2 = fmaf(ew, l2_w[j * H + k], u2);
    c2 = fmaf(eb, l2_w[j * H + k], c2);
    u3 = fmaf(ew, l3_w[j * H + k], u3);
    c3 = fmaf(eb, l3_w[j * H + k], c3);
  }
  consts[2 + k]         = u2;
  consts[2 + H + k]     = c2 + l2_b[k] + n1_b[k];
  consts[2 + 2 * H + k] = u3;
  consts[2 + 3 * H + k] = c3 + l3_b[k];
  __shared__ float sa[H], sc[H];
  sa[k] = em_w[k] * l1_w[k];
  sc[k] = em_b[k] * l1_w[k];
  __syncthreads();
  for (int s = 64; s > 0; s >>= 1) {
    if (k < s) { sa[k] += sa[k + s]; sc[k] += sc[k + s]; }
    __syncthreads();
  }
  if (k == 0) { consts[0] = sa[0]; consts[1] = sc[0] + l1_b[0]; }
}

// ------------------------- CSR build -------------------------

__global__ void hist_kernel(const int* __restrict__ dst, int* __restrict__ deg,
                            int E) {
  const int e = blockIdx.x * blockDim.x + threadIdx.x;
  if (e < E) atomicAdd(&deg[dst[e]], 1);
}

// phase 1: per-block local exclusive scan; block sums out
__global__ __launch_bounds__(1024) void scan_partial(
    const int* __restrict__ deg, int* __restrict__ rowstart,
    int* __restrict__ bsum, int N) {
  __shared__ int sd[1024];
  const int tid = threadIdx.x;
  const int idx = blockIdx.x * 1024 + tid;
  const int v = (idx < N) ? deg[idx] : 0;
  sd[tid] = v;
  __syncthreads();
  for (int off = 1; off < 1024; off <<= 1) {
    const int t = (tid >= off) ? sd[tid - off] : 0;
    __syncthreads();
    sd[tid] += t;
    __syncthreads();
  }
  if (idx < N) rowstart[idx] = sd[tid] - v;
  if (tid == 1023) bsum[blockIdx.x] = sd[1023];
}

// phase 2: one wave scans block sums (NB <= 64)
__global__ void scan_bsums(const int* __restrict__ bsum, int* __restrict__ bo,
                           int NB) {
  const int t = threadIdx.x;  // 64 threads
  const int v = (t < NB) ? bsum[t] : 0;
  int incl = v;
#pragma unroll
  for (int o = 1; o < 64; o <<= 1) {
    const int u = __shfl_up(incl, o, 64);
    if (t >= o) incl += u;
  }
  if (t < NB) bo[t] = incl - v;
  if (t == 63) bo[NB] = incl;  // grand total = E
}

// phase 3: add block offsets; fill cursor and rowstart[N]
__global__ __launch_bounds__(1024) void scan_fixup(
    int* __restrict__ rowstart, int* __restrict__ cursor,
    const int* __restrict__ bo, int N, int NB) {
  const int idx = blockIdx.x * 1024 + threadIdx.x;
  if (idx < N) {
    const int r = rowstart[idx] + bo[idx >> 10];
    rowstart[idx] = r;
    cursor[idx] = r;
  } else if (idx == N) {
    rowstart[N] = bo[NB];
  }
}

__global__ void scatter_kernel(const int* __restrict__ src,
                               const int* __restrict__ dst,
                               const float* __restrict__ ea,
                               int* __restrict__ cursor,
                               int* __restrict__ srcp,
                               float* __restrict__ eap, int E) {
  const int e = blockIdx.x * blockDim.x + threadIdx.x;
  if (e >= E) return;
  const int pos = atomicAdd(&cursor[dst[e]], 1);
  srcp[pos] = src[e];
  eap[pos] = ea[e];
}

// ------------------------- layer 1 (scalar) -------------------------
// s1[n] = x[n] + sum_{e in-edges} relu(x[src] + a1*ea + c1); wave per node
__global__ __launch_bounds__(256) void edge1_csr(
    const int* __restrict__ rowstart, const int* __restrict__ srcp,
    const float* __restrict__ eap, const float* __restrict__ x,
    const float* __restrict__ consts, float* __restrict__ s1, int N) {
  const int n = (blockIdx.x * blockDim.x + threadIdx.x) >> 6;
  const int lane = threadIdx.x & 63;
  if (n >= N) return;
  const int rs = rowstart[n], re = rowstart[n + 1];
  const float a1 = consts[0], c1 = consts[1];
  float part = 0.f;
  for (int i = rs + lane; i < re; i += 64)
    part += fmaxf(x[srcp[i]] + fmaf(a1, eap[i], c1), 0.f);
#pragma unroll
  for (int o = 32; o >= 1; o >>= 1) part += __shfl_xor(part, o, 64);
  if (lane == 0) s1[n] = x[n] + part;
}

// ------------------------- layer 2 -------------------------
// t2[n,k] = s1[n]*n1w[k] + n1b[k] + sum relu(s1[src]*n1w[k] + ea*u2[k] + c2[k])
__global__ __launch_bounds__(256) void edge2_csr(
    const int* __restrict__ rowstart, const int* __restrict__ srcp,
    const float* __restrict__ eap, const float* __restrict__ s1,
    const float* __restrict__ n1w, const float* __restrict__ n1b,
    const float* __restrict__ consts, float* __restrict__ t2, int N) {
  const int n = (blockIdx.x * blockDim.x + threadIdx.x) >> 6;
  const int lane = threadIdx.x & 63;
  if (n >= N) return;
  const int rs = rowstart[n], re = rowstart[n + 1];
  const float w0 = n1w[lane],          w1 = n1w[lane + 64];
  const float u0 = consts[2 + lane],   u1 = consts[2 + lane + 64];
  const float c0 = consts[2 + H + lane], c1 = consts[2 + H + lane + 64];
  float acc0 = 0.f, acc1 = 0.f;
  for (int base = rs; base < re; base += 64) {
    const int i = base + lane;
    float s1v = 0.f, eav = 0.f;
    if (i < re) { s1v = s1[srcp[i]]; eav = eap[i]; }
    const int cnt = min(64, re - base);
    for (int j = 0; j < cnt; ++j) {
      const float s = __shfl(s1v, j, 64);
      const float a = __shfl(eav, j, 64);
      acc0 += fmaxf(fmaf(s, w0, fmaf(a, u0, c0)), 0.f);
      acc1 += fmaxf(fmaf(s, w1, fmaf(a, u1, c1)), 0.f);
    }
  }
  const float sn = s1[n];
  t2[(size_t)n * H + lane]      = fmaf(sn, w0, n1b[lane])      + acc0;
  t2[(size_t)n * H + lane + 64] = fmaf(sn, w1, n1b[lane + 64]) + acc1;
}

// ------------------------- layer 3 -------------------------
// t3[n,k] = h2[n,k] + sum relu(h2[src,k] + ea*u3[k] + c3[k]); wave per node
__global__ __launch_bounds__(256) void edge3_csr(
    const int* __restrict__ rowstart, const int* __restrict__ srcp,
    const float* __restrict__ eap, const float* __restrict__ h2,
    const float* __restrict__ consts, float* __restrict__ t3, int N) {
  const int n = (blockIdx.x * blockDim.x + threadIdx.x) >> 6;
  const int lane = threadIdx.x & 63;
  if (n >= N) return;
  const int rs = rowstart[n], re = rowstart[n + 1];
  const float u0 = consts[2 + 2 * H + lane], u1 = consts[2 + 2 * H + lane + 64];
  const float c0 = consts[2 + 3 * H + lane], c1 = consts[2 + 3 * H + lane + 64];
  float acc0 = 0.f, acc1 = 0.f;
  int i = rs;
  for (; i + 4 <= re; i += 4) {
    const int s0 = srcp[i], s1i = srcp[i + 1], s2 = srcp[i + 2], s3 = srcp[i + 3];
    const float a0 = eap[i], a1 = eap[i + 1], a2 = eap[i + 2], a3 = eap[i + 3];
    const float h00 = h2[(size_t)s0 * H + lane];
    const float h01 = h2[(size_t)s0 * H + lane + 64];
    const float h10 = h2[(size_t)s1i * H + lane];
    const float h11 = h2[(size_t)s1i * H + lane + 64];
    const float h20 = h2[(size_t)s2 * H + lane];
    const float h21 = h2[(size_t)s2 * H + lane + 64];
    const float h30 = h2[(size_t)s3 * H + lane];
    const float h31 = h2[(size_t)s3 * H + lane + 64];
    acc0 += fmaxf(h00 + fmaf(a0, u0, c0), 0.f);
    acc1 += fmaxf(h01 + fmaf(a0, u1, c1), 0.f);
    acc0 += fmaxf(h10 + fmaf(a1, u0, c0), 0.f);
    acc1 += fmaxf(h11 + fmaf(a1, u1, c1), 0.f);
    acc0 += fmaxf(h20 + fmaf(a2, u0, c0), 0.f);
    acc1 += fmaxf(h21 + fmaf(a2, u1, c1), 0.f);
    acc0 += fmaxf(h30 + fmaf(a3, u0, c0), 0.f);
    acc1 += fmaxf(h31 + fmaf(a3, u1, c1), 0.f);
  }
  for (; i < re; ++i) {
    const int s = srcp[i];
    const float a = eap[i];
    acc0 += fmaxf(h2[(size_t)s * H + lane]      + fmaf(a, u0, c0), 0.f);
    acc1 += fmaxf(h2[(size_t)s * H + lane + 64] + fmaf(a, u1, c1), 0.f);
  }
  t3[(size_t)n * H + lane]      = h2[(size_t)n * H + lane]      + acc0;
  t3[(size_t)n * H + lane + 64] = h2[(size_t)n * H + lane + 64] + acc1;
}

// ------------------------- node MLPs -------------------------
// h2 = t2 @ n2w + n2b (in-place over buf)
__global__ __launch_bounds__(256) void mlp2_kernel(
    float* __restrict__ buf, const float* __restrict__ n2w,
    const float* __restrict__ n2b, int N) {
  __shared__ float W[H * H];
  __shared__ float t[32][H];
  const int tid = threadIdx.x;
  for (int i = tid; i < H * H; i += 256) W[i] = n2w[i];
  const int kv = tid & 31;
  const int ng = tid >> 5;
  const float4* W4 = (const float4*)W;
  const float4 bias = ((const float4*)n2b)[kv];
  for (int tile = blockIdx.x * 32; tile < N; tile += gridDim.x * 32) {
    __syncthreads();
    const int nmax = min(32, N - tile);
    for (int i = tid; i < nmax * 32; i += 256) {
      const int nn = i >> 5, j4 = i & 31;
      ((float4*)&t[nn][0])[j4] = ((const float4*)(buf + (size_t)(tile + nn) * H))[j4];
    }
    __syncthreads();
    float4 acc[4];
    acc[0] = acc[1] = acc[2] = acc[3] = make_float4(0.f, 0.f, 0.f, 0.f);
    for (int j = 0; j < H; j += 4) {
      const float4 w0 = W4[(j + 0) * 32 + kv];
      const float4 w1 = W4[(j + 1) * 32 + kv];
      const float4 w2 = W4[(j + 2) * 32 + kv];
      const float4 w3 = W4[(j + 3) * 32 + kv];
#pragma unroll
      for (int m = 0; m < 4; ++m) {
        const float4 tm = *(const float4*)&t[4 * ng + m][j];
        acc[m] = f4fma(tm.x, w0, acc[m]);
        acc[m] = f4fma(tm.y, w1, acc[m]);
        acc[m] = f4fma(tm.z, w2, acc[m]);
        acc[m] = f4fma(tm.w, w3, acc[m]);
      }
    }
#pragma unroll
    for (int m = 0; m < 4; ++m) {
      const int nn = 4 * ng + m;
      if (nn < nmax) {
        float4 o;
        o.x = acc[m].x + bias.x; o.y = acc[m].y + bias.y;
        o.z = acc[m].z + bias.z; o.w = acc[m].w + bias.w;
        ((float4*)buf)[(size_t)(tile + nn) * 32 + kv] = o;
      }
    }
  }
}

// h3 = t3 @ n3w + n3b; p[n]=h3.dec_w[:128]; q[n]=h3.dec_w[128:]
__global__ __launch_bounds__(256) void mlp3_kernel(
    const float* __restrict__ t3, const float* __restrict__ n3w,
    const float* __restrict__ n3b, const float* __restrict__ dec_w,
    float* __restrict__ p, float* __restrict__ q, int N) {
  __shared__ float W[H * H];
  __shared__ float t[32][H];
  const int tid = threadIdx.x;
  for (int i = tid; i < H * H; i += 256) W[i] = n3w[i];
  const int kv = tid & 31;
  const int ng = tid >> 5;
  const float4* W4 = (const float4*)W;
  const float4 bias = ((const float4*)n3b)[kv];
  const float4 dwA = ((const float4*)dec_w)[kv];
  const float4 dwB = ((const float4*)(dec_w + H))[kv];
  for (int tile = blockIdx.x * 32; tile < N; tile += gridDim.x * 32) {
    __syncthreads();
    const int nmax = min(32, N - tile);
    for (int i = tid; i < nmax * 32; i += 256) {
      const int nn = i >> 5, j4 = i & 31;
      ((float4*)&t[nn][0])[j4] = ((const float4*)(t3 + (size_t)(tile + nn) * H))[j4];
    }
    __syncthreads();
    float4 acc[4];
    acc[0] = acc[1] = acc[2] = acc[3] = make_float4(0.f, 0.f, 0.f, 0.f);
    for (int j = 0; j < H; j += 4) {
      const float4 w0 = W4[(j + 0) * 32 + kv];
      const float4 w1 = W4[(j + 1) * 32 + kv];
      const float4 w2 = W4[(j + 2) * 32 + kv];
      const float4 w3 = W4[(j + 3) * 32 + kv];
#pragma unroll
      for (int m = 0; m < 4; ++m) {
        const float4 tm = *(const float4*)&t[4 * ng + m][j];
        acc[m] = f4fma(tm.x, w0, acc[m]);
        acc[m] = f4fma(tm.y, w1, acc[m]);
        acc[m] = f4fma(tm.z, w2, acc[m]);
        acc[m] = f4fma(tm.w, w3, acc[m]);
      }
    }
#pragma unroll
    for (int m = 0; m < 4; ++m) {
      float4 h;
      h.x = acc[m].x + bias.x; h.y = acc[m].y + bias.y;
      h.z = acc[m].z + bias.z; h.w = acc[m].w + bias.w;
      float pd = h.x * dwA.x + h.y * dwA.y + h.z * dwA.z + h.w * dwA.w;
      float qd = h.x * dwB.x + h.y * dwB.y + h.z * dwB.z + h.w * dwB.w;
#pragma unroll
      for (int o = 16; o >= 1; o >>= 1) {
        pd += __shfl_xor(pd, o, 64);
        qd += __shfl_xor(qd, o, 64);
      }
      const int n = tile + 4 * ng + m;
      if (kv == 0 && 4 * ng + m < nmax) { p[n] = pd; q[n] = qd; }
    }
  }
}

__global__ void final_kernel(const int* __restrict__ src,
                             const int* __restrict__ dst,
                             const float* __restrict__ p,
                             const float* __restrict__ q,
                             const float* __restrict__ dec_b,
                             float* __restrict__ out, int E) {
  const int e = blockIdx.x * blockDim.x + threadIdx.x;
  if (e < E) out[e] = p[src[e]] + q[dst[e]] + dec_b[0];
}

extern "C" void kernel_launch(void* const* d_in, const int* in_sizes, int n_in,
                              void* d_out, int out_size, void* d_ws, size_t ws_size,
                              hipStream_t stream) {
  const float* x     = (const float*)d_in[0];
  const int*   ei    = (const int*)d_in[1];
  const float* ea    = (const float*)d_in[2];
  const float* em_w  = (const float*)d_in[3];
  const float* em_b  = (const float*)d_in[4];
  const float* l1_w  = (const float*)d_in[5];
  const float* l1_b  = (const float*)d_in[6];
  const float* n1_w  = (const float*)d_in[7];
  const float* n1_b  = (const float*)d_in[8];
  const float* l2_w  = (const float*)d_in[9];
  const float* l2_b  = (const float*)d_in[10];
  const float* n2_w  = (const float*)d_in[11];
  const float* n2_b  = (const float*)d_in[12];
  const float* l3_w  = (const float*)d_in[13];
  const float* l3_b  = (const float*)d_in[14];
  const float* n3_w  = (const float*)d_in[15];
  const float* n3_b  = (const float*)d_in[16];
  const float* dec_w = (const float*)d_in[17];
  const float* dec_b = (const float*)d_in[18];
  float* out = (float*)d_out;

  const int N = in_sizes[0];
  const int E = in_sizes[2];
  const int* src = ei;
  const int* dst = ei + E;

  float* ws       = (float*)d_ws;
  float* consts   = ws;
  float* bufA     = ws + 1024;                      // t2 -> h2
  float* bufB     = bufA + (size_t)N * H;           // t3 (first N ints = cursor)
  float* s1       = bufB + (size_t)N * H;
  float* p        = s1 + N;
  float* q        = p + N;
  int*   deg      = (int*)(q + N);
  int*   rowstart = deg + N;                        // N+1
  int*   srcp     = rowstart + N + 1;               // E
  float* eap      = (float*)(srcp + E);             // E
  int*   bsum     = (int*)(eap + E);                // 64
  int*   bo       = bsum + 64;                      // 65
  int*   cursor   = (int*)bufB;                     // aliased: dead before edge3

  const int NB = (N + 1023) / 1024;  // 49 for N=50000 (<= 64)

  hipMemsetAsync(deg, 0, (size_t)N * sizeof(int), stream);

  precompute_kernel<<<1, 128, 0, stream>>>(em_w, em_b, l1_w, l1_b, l2_w, l2_b,
                                           n1_b, l3_w, l3_b, consts);
  hist_kernel<<<(E + 255) / 256, 256, 0, stream>>>(dst, deg, E);
  scan_partial<<<NB, 1024, 0, stream>>>(deg, rowstart, bsum, N);
  scan_bsums<<<1, 64, 0, stream>>>(bsum, bo, NB);
  scan_fixup<<<NB, 1024, 0, stream>>>(rowstart, cursor, bo, N, NB);
  scatter_kernel<<<(E + 255) / 256, 256, 0, stream>>>(src, dst, ea, cursor,
                                                      srcp, eap, E);

  const int nwblocks = (N + 3) / 4;  // 4 waves (nodes) per 256-thread block
  edge1_csr<<<nwblocks, 256, 0, stream>>>(rowstart, srcp, eap, x, consts, s1, N);
  edge2_csr<<<nwblocks, 256, 0, stream>>>(rowstart, srcp, eap, s1, n1_w, n1_b,
                                          consts, bufA, N);
  mlp2_kernel<<<512, 256, 0, stream>>>(bufA, n2_w, n2_b, N);
  edge3_csr<<<nwblocks, 256, 0, stream>>>(rowstart, srcp, eap, bufA, consts,
                                          bufB, N);
  mlp3_kernel<<<512, 256, 0, stream>>>(bufB, n3_w, n3_b, dec_w, p, q, N);
  final_kernel<<<(E + 255) / 256, 256, 0, stream>>>(src, dst, p, q, dec_b, out, E);
}

// Round 4
// 335.179 us; speedup vs baseline: 2.7069x; 1.1022x over previous
//
#include <hip/hip_runtime.h>

#define H 128

// ---------------------------------------------------------------------------
// R3: (a) scatter payload packed as int2 (one 8B scattered store per edge,
// was 2x4B partial lines -> WRITE_SIZE 82MB); (b) precompute folded into
// hist (block 0), scan_bsums folded into scan_fixup (-2 dispatches);
// (c) h2 stored bf16 -> edge3 gather traffic halved.
//
// Workspace layout (4-byte units):
//   consts[1024] : [0]=a1,[1]=c1,[2..]=u2,c2,u3,c3
//   bufA[N*128]  : t2 (edge2 out, f32)
//   bufB[N*128]  : t3 (edge3 out, f32); first N ints double as scatter cursor
//   h2b[N*64]    : h2 as bf16 (ushort, row stride 128)
//   s1[N], p[N], q[N]
//   deg[N], rowstart[N+1], sp[2*E] (int2 payload), bsum[64]
// ---------------------------------------------------------------------------

__device__ __forceinline__ float4 f4fma(float s, float4 w, float4 a) {
  a.x = fmaf(s, w.x, a.x); a.y = fmaf(s, w.y, a.y);
  a.z = fmaf(s, w.z, a.z); a.w = fmaf(s, w.w, a.w);
  return a;
}

__device__ __forceinline__ float bf2f(unsigned short v) {
  return __uint_as_float(((unsigned)v) << 16);
}

__device__ __forceinline__ unsigned bf16pair(float a, float b) {
  unsigned ua = __float_as_uint(a), ub = __float_as_uint(b);
  ua = (ua + 0x7FFFu + ((ua >> 16) & 1u)) >> 16;   // RNE
  ub = (ub + 0x7FFFu + ((ub >> 16) & 1u)) >> 16;
  return (ua & 0xFFFFu) | (ub << 16);
}

// block 0: precompute folded constants; blocks 1..: dst histogram
__global__ void hist_pre_kernel(
    const int* __restrict__ dst, int* __restrict__ deg, int E,
    const float* __restrict__ em_w, const float* __restrict__ em_b,
    const float* __restrict__ l1_w, const float* __restrict__ l1_b,
    const float* __restrict__ l2_w, const float* __restrict__ l2_b,
    const float* __restrict__ n1_b,
    const float* __restrict__ l3_w, const float* __restrict__ l3_b,
    float* __restrict__ consts) {
  if (blockIdx.x == 0) {
    const int k = threadIdx.x;
    __shared__ float sa[H], sc[H];
    if (k < H) {
      float u2 = 0.f, c2 = 0.f, u3 = 0.f, c3 = 0.f;
      for (int j = 0; j < H; ++j) {
        const float ew = em_w[j], eb = em_b[j];
        u2 = fmaf(ew, l2_w[j * H + k], u2);
        c2 = fmaf(eb, l2_w[j * H + k], c2);
        u3 = fmaf(ew, l3_w[j * H + k], u3);
        c3 = fmaf(eb, l3_w[j * H + k], c3);
      }
      consts[2 + k]         = u2;
      consts[2 + H + k]     = c2 + l2_b[k] + n1_b[k];
      consts[2 + 2 * H + k] = u3;
      consts[2 + 3 * H + k] = c3 + l3_b[k];
      sa[k] = em_w[k] * l1_w[k];
      sc[k] = em_b[k] * l1_w[k];
    }
    __syncthreads();
    for (int s = 64; s > 0; s >>= 1) {
      if (k < s) { sa[k] += sa[k + s]; sc[k] += sc[k + s]; }
      __syncthreads();
    }
    if (k == 0) { consts[0] = sa[0]; consts[1] = sc[0] + l1_b[0]; }
  } else {
    const int e = (blockIdx.x - 1) * blockDim.x + threadIdx.x;
    if (e < E) atomicAdd(&deg[dst[e]], 1);
  }
}

// phase 1: per-block local exclusive scan; block sums out
__global__ __launch_bounds__(1024) void scan_partial(
    const int* __restrict__ deg, int* __restrict__ rowstart,
    int* __restrict__ bsum, int N) {
  __shared__ int sd[1024];
  const int tid = threadIdx.x;
  const int idx = blockIdx.x * 1024 + tid;
  const int v = (idx < N) ? deg[idx] : 0;
  sd[tid] = v;
  __syncthreads();
  for (int off = 1; off < 1024; off <<= 1) {
    const int t = (tid >= off) ? sd[tid - off] : 0;
    __syncthreads();
    sd[tid] += t;
    __syncthreads();
  }
  if (idx < N) rowstart[idx] = sd[tid] - v;
  if (tid == 1023) bsum[blockIdx.x] = sd[1023];
}

// phase 2+3 fused: each block wave-scans bsum (NB<=64) for its own offset
__global__ __launch_bounds__(1024) void scan_fixup(
    int* __restrict__ rowstart, int* __restrict__ cursor,
    const int* __restrict__ bsum, int N, int NB) {
  __shared__ int s_off, s_tot;
  const int tid = threadIdx.x;
  if (tid < 64) {
    const int v = (tid < NB) ? bsum[tid] : 0;
    int incl = v;
#pragma unroll
    for (int o = 1; o < 64; o <<= 1) {
      const int u = __shfl_up(incl, o, 64);
      if (tid >= o) incl += u;
    }
    if (tid == (int)blockIdx.x) s_off = incl - v;  // sum_{i<b}
    if (tid == 63) s_tot = incl;                   // grand total = E
  }
  __syncthreads();
  const int idx = blockIdx.x * 1024 + tid;
  if (idx < N) {
    const int r = rowstart[idx] + s_off;
    rowstart[idx] = r;
    cursor[idx] = r;
  } else if (idx == N) {
    rowstart[N] = s_tot;
  }
}

__global__ void scatter_kernel(const int* __restrict__ src,
                               const int* __restrict__ dst,
                               const float* __restrict__ ea,
                               int* __restrict__ cursor,
                               int2* __restrict__ sp, int E) {
  const int e = blockIdx.x * blockDim.x + threadIdx.x;
  if (e >= E) return;
  const int pos = atomicAdd(&cursor[dst[e]], 1);
  sp[pos] = make_int2(src[e], __float_as_int(ea[e]));
}

// ------------------------- layer 1 (scalar) -------------------------
// s1[n] = x[n] + sum relu(x[src] + a1*ea + c1); wave per node
__global__ __launch_bounds__(256) void edge1_csr(
    const int* __restrict__ rowstart, const int2* __restrict__ sp,
    const float* __restrict__ x, const float* __restrict__ consts,
    float* __restrict__ s1, int N) {
  const int n = (blockIdx.x * blockDim.x + threadIdx.x) >> 6;
  const int lane = threadIdx.x & 63;
  if (n >= N) return;
  const int rs = rowstart[n], re = rowstart[n + 1];
  const float a1 = consts[0], c1 = consts[1];
  float part = 0.f;
  for (int i = rs + lane; i < re; i += 64) {
    const int2 sv = sp[i];
    part += fmaxf(x[sv.x] + fmaf(a1, __int_as_float(sv.y), c1), 0.f);
  }
#pragma unroll
  for (int o = 32; o >= 1; o >>= 1) part += __shfl_xor(part, o, 64);
  if (lane == 0) s1[n] = x[n] + part;
}

// ------------------------- layer 2 -------------------------
// t2[n,k] = s1[n]*n1w[k] + n1b[k] + sum relu(s1[src]*n1w[k] + ea*u2[k] + c2[k])
__global__ __launch_bounds__(256) void edge2_csr(
    const int* __restrict__ rowstart, const int2* __restrict__ sp,
    const float* __restrict__ s1, const float* __restrict__ n1w,
    const float* __restrict__ n1b, const float* __restrict__ consts,
    float* __restrict__ t2, int N) {
  const int n = (blockIdx.x * blockDim.x + threadIdx.x) >> 6;
  const int lane = threadIdx.x & 63;
  if (n >= N) return;
  const int rs = rowstart[n], re = rowstart[n + 1];
  const float w0 = n1w[lane],            w1 = n1w[lane + 64];
  const float u0 = consts[2 + lane],     u1 = consts[2 + lane + 64];
  const float c0 = consts[2 + H + lane], c1 = consts[2 + H + lane + 64];
  float acc0 = 0.f, acc1 = 0.f;
  for (int base = rs; base < re; base += 64) {
    const int i = base + lane;
    float s1v = 0.f, eav = 0.f;
    if (i < re) {
      const int2 sv = sp[i];
      s1v = s1[sv.x];
      eav = __int_as_float(sv.y);
    }
    const int cnt = min(64, re - base);
    for (int j = 0; j < cnt; ++j) {
      const float s = __shfl(s1v, j, 64);
      const float a = __shfl(eav, j, 64);
      acc0 += fmaxf(fmaf(s, w0, fmaf(a, u0, c0)), 0.f);
      acc1 += fmaxf(fmaf(s, w1, fmaf(a, u1, c1)), 0.f);
    }
  }
  const float sn = s1[n];
  t2[(size_t)n * H + lane]      = fmaf(sn, w0, n1b[lane])      + acc0;
  t2[(size_t)n * H + lane + 64] = fmaf(sn, w1, n1b[lane + 64]) + acc1;
}

// ------------------------- layer 3 (bf16 h2 gather) -------------------------
// t3[n,k] = h2[n,k] + sum relu(h2[src,k] + ea*u3[k] + c3[k]); wave per node
// lane handles k = 2*lane, 2*lane+1 (one ushort2 load per row per lane)
__global__ __launch_bounds__(256) void edge3_csr(
    const int* __restrict__ rowstart, const int2* __restrict__ sp,
    const unsigned short* __restrict__ h2b, const float* __restrict__ consts,
    float* __restrict__ t3, int N) {
  const int n = (blockIdx.x * blockDim.x + threadIdx.x) >> 6;
  const int lane = threadIdx.x & 63;
  if (n >= N) return;
  const int rs = rowstart[n], re = rowstart[n + 1];
  const int k0 = 2 * lane;
  const float u0 = consts[2 + 2 * H + k0], u1 = consts[2 + 2 * H + k0 + 1];
  const float c0 = consts[2 + 3 * H + k0], c1 = consts[2 + 3 * H + k0 + 1];
  float acc0 = 0.f, acc1 = 0.f;
  int i = rs;
  for (; i + 4 <= re; i += 4) {
    const int2 e0 = sp[i], e1 = sp[i + 1], e2 = sp[i + 2], e3 = sp[i + 3];
    const ushort2 h0 = *(const ushort2*)&h2b[(size_t)e0.x * H + k0];
    const ushort2 h1 = *(const ushort2*)&h2b[(size_t)e1.x * H + k0];
    const ushort2 h2v = *(const ushort2*)&h2b[(size_t)e2.x * H + k0];
    const ushort2 h3 = *(const ushort2*)&h2b[(size_t)e3.x * H + k0];
    const float a0 = __int_as_float(e0.y), a1 = __int_as_float(e1.y);
    const float a2 = __int_as_float(e2.y), a3 = __int_as_float(e3.y);
    acc0 += fmaxf(bf2f(h0.x) + fmaf(a0, u0, c0), 0.f);
    acc1 += fmaxf(bf2f(h0.y) + fmaf(a0, u1, c1), 0.f);
    acc0 += fmaxf(bf2f(h1.x) + fmaf(a1, u0, c0), 0.f);
    acc1 += fmaxf(bf2f(h1.y) + fmaf(a1, u1, c1), 0.f);
    acc0 += fmaxf(bf2f(h2v.x) + fmaf(a2, u0, c0), 0.f);
    acc1 += fmaxf(bf2f(h2v.y) + fmaf(a2, u1, c1), 0.f);
    acc0 += fmaxf(bf2f(h3.x) + fmaf(a3, u0, c0), 0.f);
    acc1 += fmaxf(bf2f(h3.y) + fmaf(a3, u1, c1), 0.f);
  }
  for (; i < re; ++i) {
    const int2 ev = sp[i];
    const ushort2 hv = *(const ushort2*)&h2b[(size_t)ev.x * H + k0];
    const float a = __int_as_float(ev.y);
    acc0 += fmaxf(bf2f(hv.x) + fmaf(a, u0, c0), 0.f);
    acc1 += fmaxf(bf2f(hv.y) + fmaf(a, u1, c1), 0.f);
  }
  const ushort2 hn = *(const ushort2*)&h2b[(size_t)n * H + k0];
  float2 o;
  o.x = bf2f(hn.x) + acc0;
  o.y = bf2f(hn.y) + acc1;
  *(float2*)&t3[(size_t)n * H + k0] = o;
}

// ------------------------- node MLPs -------------------------
// h2b = bf16(t2 @ n2w + n2b)
__global__ __launch_bounds__(256) void mlp2_kernel(
    const float* __restrict__ t2, unsigned short* __restrict__ h2b,
    const float* __restrict__ n2w, const float* __restrict__ n2b, int N) {
  __shared__ float W[H * H];
  __shared__ float t[32][H];
  const int tid = threadIdx.x;
  for (int i = tid; i < H * H; i += 256) W[i] = n2w[i];
  const int kv = tid & 31;
  const int ng = tid >> 5;
  const float4* W4 = (const float4*)W;
  const float4 bias = ((const float4*)n2b)[kv];
  for (int tile = blockIdx.x * 32; tile < N; tile += gridDim.x * 32) {
    __syncthreads();
    const int nmax = min(32, N - tile);
    for (int i = tid; i < nmax * 32; i += 256) {
      const int nn = i >> 5, j4 = i & 31;
      ((float4*)&t[nn][0])[j4] = ((const float4*)(t2 + (size_t)(tile + nn) * H))[j4];
    }
    __syncthreads();
    float4 acc[4];
    acc[0] = acc[1] = acc[2] = acc[3] = make_float4(0.f, 0.f, 0.f, 0.f);
    for (int j = 0; j < H; j += 4) {
      const float4 w0 = W4[(j + 0) * 32 + kv];
      const float4 w1 = W4[(j + 1) * 32 + kv];
      const float4 w2 = W4[(j + 2) * 32 + kv];
      const float4 w3 = W4[(j + 3) * 32 + kv];
#pragma unroll
      for (int m = 0; m < 4; ++m) {
        const float4 tm = *(const float4*)&t[4 * ng + m][j];
        acc[m] = f4fma(tm.x, w0, acc[m]);
        acc[m] = f4fma(tm.y, w1, acc[m]);
        acc[m] = f4fma(tm.z, w2, acc[m]);
        acc[m] = f4fma(tm.w, w3, acc[m]);
      }
    }
#pragma unroll
    for (int m = 0; m < 4; ++m) {
      const int nn = 4 * ng + m;
      if (nn < nmax) {
        uint2 st;
        st.x = bf16pair(acc[m].x + bias.x, acc[m].y + bias.y);
        st.y = bf16pair(acc[m].z + bias.z, acc[m].w + bias.w);
        ((uint2*)(h2b + (size_t)(tile + nn) * H))[kv] = st;
      }
    }
  }
}

// h3 = t3 @ n3w + n3b; p[n]=h3.dec_w[:128]; q[n]=h3.dec_w[128:]
__global__ __launch_bounds__(256) void mlp3_kernel(
    const float* __restrict__ t3, const float* __restrict__ n3w,
    const float* __restrict__ n3b, const float* __restrict__ dec_w,
    float* __restrict__ p, float* __restrict__ q, int N) {
  __shared__ float W[H * H];
  __shared__ float t[32][H];
  const int tid = threadIdx.x;
  for (int i = tid; i < H * H; i += 256) W[i] = n3w[i];
  const int kv = tid & 31;
  const int ng = tid >> 5;
  const float4* W4 = (const float4*)W;
  const float4 bias = ((const float4*)n3b)[kv];
  const float4 dwA = ((const float4*)dec_w)[kv];
  const float4 dwB = ((const float4*)(dec_w + H))[kv];
  for (int tile = blockIdx.x * 32; tile < N; tile += gridDim.x * 32) {
    __syncthreads();
    const int nmax = min(32, N - tile);
    for (int i = tid; i < nmax * 32; i += 256) {
      const int nn = i >> 5, j4 = i & 31;
      ((float4*)&t[nn][0])[j4] = ((const float4*)(t3 + (size_t)(tile + nn) * H))[j4];
    }
    __syncthreads();
    float4 acc[4];
    acc[0] = acc[1] = acc[2] = acc[3] = make_float4(0.f, 0.f, 0.f, 0.f);
    for (int j = 0; j < H; j += 4) {
      const float4 w0 = W4[(j + 0) * 32 + kv];
      const float4 w1 = W4[(j + 1) * 32 + kv];
      const float4 w2 = W4[(j + 2) * 32 + kv];
      const float4 w3 = W4[(j + 3) * 32 + kv];
#pragma unroll
      for (int m = 0; m < 4; ++m) {
        const float4 tm = *(const float4*)&t[4 * ng + m][j];
        acc[m] = f4fma(tm.x, w0, acc[m]);
        acc[m] = f4fma(tm.y, w1, acc[m]);
        acc[m] = f4fma(tm.z, w2, acc[m]);
        acc[m] = f4fma(tm.w, w3, acc[m]);
      }
    }
#pragma unroll
    for (int m = 0; m < 4; ++m) {
      float4 h;
      h.x = acc[m].x + bias.x; h.y = acc[m].y + bias.y;
      h.z = acc[m].z + bias.z; h.w = acc[m].w + bias.w;
      float pd = h.x * dwA.x + h.y * dwA.y + h.z * dwA.z + h.w * dwA.w;
      float qd = h.x * dwB.x + h.y * dwB.y + h.z * dwB.z + h.w * dwB.w;
#pragma unroll
      for (int o = 16; o >= 1; o >>= 1) {
        pd += __shfl_xor(pd, o, 64);
        qd += __shfl_xor(qd, o, 64);
      }
      const int n = tile + 4 * ng + m;
      if (kv == 0 && 4 * ng + m < nmax) { p[n] = pd; q[n] = qd; }
    }
  }
}

__global__ void final_kernel(const int* __restrict__ src,
                             const int* __restrict__ dst,
                             const float* __restrict__ p,
                             const float* __restrict__ q,
                             const float* __restrict__ dec_b,
                             float* __restrict__ out, int E) {
  const int e = blockIdx.x * blockDim.x + threadIdx.x;
  if (e < E) out[e] = p[src[e]] + q[dst[e]] + dec_b[0];
}

extern "C" void kernel_launch(void* const* d_in, const int* in_sizes, int n_in,
                              void* d_out, int out_size, void* d_ws, size_t ws_size,
                              hipStream_t stream) {
  const float* x     = (const float*)d_in[0];
  const int*   ei    = (const int*)d_in[1];
  const float* ea    = (const float*)d_in[2];
  const float* em_w  = (const float*)d_in[3];
  const float* em_b  = (const float*)d_in[4];
  const float* l1_w  = (const float*)d_in[5];
  const float* l1_b  = (const float*)d_in[6];
  const float* n1_w  = (const float*)d_in[7];
  const float* n1_b  = (const float*)d_in[8];
  const float* l2_w  = (const float*)d_in[9];
  const float* l2_b  = (const float*)d_in[10];
  const float* n2_w  = (const float*)d_in[11];
  const float* n2_b  = (const float*)d_in[12];
  const float* l3_w  = (const float*)d_in[13];
  const float* l3_b  = (const float*)d_in[14];
  const float* n3_w  = (const float*)d_in[15];
  const float* n3_b  = (const float*)d_in[16];
  const float* dec_w = (const float*)d_in[17];
  const float* dec_b = (const float*)d_in[18];
  float* out = (float*)d_out;

  const int N = in_sizes[0];
  const int E = in_sizes[2];
  const int* src = ei;
  const int* dst = ei + E;

  float* ws       = (float*)d_ws;
  float* consts   = ws;
  float* bufA     = ws + 1024;                      // t2 (f32)
  float* bufB     = bufA + (size_t)N * H;           // t3 (f32); head = cursor
  unsigned short* h2b = (unsigned short*)(bufB + (size_t)N * H);  // N*128 bf16
  float* s1       = (float*)(h2b + (size_t)N * H);
  float* p        = s1 + N;
  float* q        = p + N;
  int*   deg      = (int*)(q + N);
  int*   rowstart = deg + N;                        // N+1
  int2*  sp       = (int2*)(rowstart + N + 1);      // E int2
  int*   bsum     = (int*)(sp + E);                 // 64
  int*   cursor   = (int*)bufB;                     // aliased: dead before edge3

  const int NB = (N + 1023) / 1024;  // 49 for N=50000 (<= 64)

  hipMemsetAsync(deg, 0, (size_t)N * sizeof(int), stream);

  hist_pre_kernel<<<1 + (E + 255) / 256, 256, 0, stream>>>(
      dst, deg, E, em_w, em_b, l1_w, l1_b, l2_w, l2_b, n1_b, l3_w, l3_b, consts);
  scan_partial<<<NB, 1024, 0, stream>>>(deg, rowstart, bsum, N);
  scan_fixup<<<NB, 1024, 0, stream>>>(rowstart, cursor, bsum, N, NB);
  scatter_kernel<<<(E + 255) / 256, 256, 0, stream>>>(src, dst, ea, cursor, sp, E);

  const int nwblocks = (N + 3) / 4;  // 4 waves (nodes) per 256-thread block
  edge1_csr<<<nwblocks, 256, 0, stream>>>(rowstart, sp, x, consts, s1, N);
  edge2_csr<<<nwblocks, 256, 0, stream>>>(rowstart, sp, s1, n1_w, n1_b, consts,
                                          bufA, N);
  mlp2_kernel<<<512, 256, 0, stream>>>(bufA, h2b, n2_w, n2_b, N);
  edge3_csr<<<nwblocks, 256, 0, stream>>>(rowstart, sp, h2b, consts, bufB, N);
  mlp3_kernel<<<512, 256, 0, stream>>>(bufB, n3_w, n3_b, dec_w, p, q, N);
  final_kernel<<<(E + 255) / 256, 256, 0, stream>>>(src, dst, p, q, dec_b, out, E);
}